// Round 3
// baseline (4230.072 us; speedup 1.0000x reference)
//
#include <hip/hip_runtime.h>
#include <stdint.h>
#include <math.h>

#define HH   512
#define BB   64
#define TT   2000
#define NEXC 409          // int(0.8 * 512)
#define SLICE  128        // hidden units owned per block
#define NBLK   (BB * 4)   // 256 blocks = 1 per CU

// Python-float constants, rounded to f32 exactly as the reference does.
constexpr float ALPHA_F     = 0.1f;
constexpr float IN_SCALE_F  = (float)4.4721359549995794e-03;
constexpr float REC_SCALE_F = (float)4.4721359549995794e-02;
constexpr float SQRT2_F     = 1.41421356237309515f;
constexpr float U_LO        = -0x1.fffffep-1f;

struct U2 { uint32_t a, b; };

__host__ __device__ constexpr uint32_t rotl32(uint32_t x, int d) {
  return (x << d) | (x >> (32 - d));
}

// JAX Threefry-2x32, 20 rounds.
__host__ __device__ constexpr U2 tf2x32(uint32_t k0, uint32_t k1,
                                        uint32_t x0, uint32_t x1) {
  uint32_t ks[3] = {k0, k1, k0 ^ k1 ^ 0x1BD11BDAu};
  const int R[2][4] = {{13, 15, 26, 6}, {17, 29, 16, 24}};
  x0 += ks[0]; x1 += ks[1];
  for (int g = 0; g < 5; ++g) {
    const int* r = R[g & 1];
    for (int i = 0; i < 4; ++i) { x0 += x1; x1 = rotl32(x1, r[i]); x1 ^= x0; }
    x0 += ks[(g + 1) % 3];
    x1 += ks[(g + 2) % 3] + (uint32_t)(g + 1);
  }
  return U2{x0, x1};
}

constexpr U2 KIN_  = tf2x32(0u, 42u, 0u, 0u);
constexpr U2 KREC_ = tf2x32(0u, 42u, 0u, 1u);
constexpr uint32_t KIN0 = KIN_.a,  KIN1 = KIN_.b;
constexpr uint32_t KRC0 = KREC_.a, KRC1 = KREC_.b;

__device__ __forceinline__ float jax_normal(uint32_t k0, uint32_t k1, uint32_t idx) {
  U2 o = tf2x32(k0, k1, 0u, idx);
  uint32_t bits = o.a ^ o.b;
  float f = __uint_as_float((bits >> 9) | 0x3f800000u) - 1.0f;  // [0,1)
  float u = fmaxf(U_LO, f * 2.0f + U_LO);
  float w = -log1pf(-u * u);
  float p;
  if (w < 5.0f) {
    w = w - 2.5f;
    p =             2.81022636e-08f;
    p = fmaf(p, w,  3.43273939e-07f);
    p = fmaf(p, w, -3.5233877e-06f);
    p = fmaf(p, w, -4.39150654e-06f);
    p = fmaf(p, w,  0.00021858087f);
    p = fmaf(p, w, -0.00125372503f);
    p = fmaf(p, w, -0.00417768164f);
    p = fmaf(p, w,  0.246640727f);
    p = fmaf(p, w,  1.50140941f);
  } else {
    w = sqrtf(w) - 3.0f;
    p =            -0.000200214257f;
    p = fmaf(p, w,  0.000100950558f);
    p = fmaf(p, w,  0.00134934322f);
    p = fmaf(p, w, -0.00367342844f);
    p = fmaf(p, w,  0.00573950773f);
    p = fmaf(p, w, -0.0076224613f);
    p = fmaf(p, w,  0.00943887047f);
    p = fmaf(p, w,  1.00167406f);
    p = fmaf(p, w,  2.83297682f);
  }
  return SQRT2_F * (p * u);
}

// Workspace: pub[2][BB][HH] uint64 words, each = (step_tag << 32) | f32bits(relu(h)).
#define PUB_WORDS (2 * BB * HH)
#define PUB_BYTES (PUB_WORDS * 8)   // 512 KB

__global__ __launch_bounds__(512, 2)
void zrnn_main(const float* __restrict__ i_stim, const float* __restrict__ i_cc,
               const float* __restrict__ hidden0,
               const float* __restrict__ w_ih, const float* __restrict__ w_hh,
               const float* __restrict__ b_hh,
               const float* __restrict__ w_ho, const float* __restrict__ b_ho,
               float* __restrict__ outs, float* __restrict__ hids,
               uint64_t* __restrict__ pub) {
  // blockIdx -> (batch b, slice s); same-batch siblings share blockIdx%8 so they
  // land on one XCD under round-robin dispatch (perf-only assumption).
  const int bid  = blockIdx.x;
  const int low3 = bid & 7;
  const int q    = bid >> 3;
  const int s    = q & 3;
  const int b    = ((q >> 2) << 3) + low3;
  const int tid  = threadIdx.x;
  const int lane = tid & 63;
  const int wv   = tid >> 6;          // wave id = i-chunk id

  const int  ownLo = s * SLICE;
  const bool isOwn = (tid >= ownLo) && (tid < ownLo + SLICE);
  const int  jloc  = tid - ownLo;     // valid only when isOwn

  __shared__ float stim_s[TT];
  __shared__ float cc_s[TT];
  __shared__ float red[2][8][SLICE];  // parity-double-buffered matvec partials
  __shared__ float nbuf[4][SLICE];    // n_rec (owner-private slots)
  __shared__ float nin_s[4][2];       // n_in
  __shared__ float obuf[8];           // rotating output-duty partials

  // Preload this batch's input streams (16 KB LDS), coalesced.
  for (int idx = tid; idx < TT; idx += 512) {
    stim_s[idx] = i_stim[b * TT + idx];
    cc_s[idx]   = i_cc[b * TT + idx];
  }

  // Weight slice in REGISTERS: thread (wv,lane) holds wt[i][j] for
  // i in [64*wv, 64*wv+64), j in {jA, jB}.  wt[i][j] = |w_hh[j][i]|*(i!=j)*ei[i].
  const int jA = ownLo + lane;
  const int jB = jA + 64;
  const int i0 = wv * 64;
  float wA[64], wB[64];
  #pragma unroll
  for (int k4 = 0; k4 < 16; ++k4) {
    float4 a4 = *reinterpret_cast<const float4*>(&w_hh[jA * HH + i0 + k4 * 4]);
    float4 b4 = *reinterpret_cast<const float4*>(&w_hh[jB * HH + i0 + k4 * 4]);
    const float av[4] = {a4.x, a4.y, a4.z, a4.w};
    const float bv[4] = {b4.x, b4.y, b4.z, b4.w};
    #pragma unroll
    for (int c = 0; c < 4; ++c) {
      const int i = i0 + k4 * 4 + c;
      float va = (i == jA) ? 0.0f : fabsf(av[c]);
      float vb = (i == jB) ? 0.0f : fabsf(bv[c]);
      wA[k4 * 4 + c] = (i < NEXC) ? va : -va;
      wB[k4 * 4 + c] = (i < NEXC) ? vb : -vb;
    }
  }

  // Owners are the threads whose rv index is their own hidden unit: jown == tid.
  float h = 0.0f, wih0 = 0.0f, wih1 = 0.0f, bhh = 0.0f;
  if (isOwn) {
    h    = hidden0[b * HH + tid];
    wih0 = w_ih[tid * 2 + 0];
    wih1 = w_ih[tid * 2 + 1];
    bhh  = b_hh[tid];
  }
  const float who_f = w_ho[tid];
  const float bho   = b_ho[0];

  // rv: lane mapping i = tid; primed from hidden0.
  float rv = fmaxf(hidden0[b * HH + tid], 0.0f);

  // Noise prefill: owners fill their private nbuf slots for steps 0..3;
  // owner lanes 0..7 fill nin_s.
  if (isOwn) {
    #pragma unroll
    for (int tp = 0; tp < 4; ++tp)
      nbuf[tp][jloc] = jax_normal(KRC0, KRC1,
          (uint32_t)tp * (uint32_t)(BB * HH) + (uint32_t)(b * HH + tid));
    if (jloc < 8)
      nin_s[jloc >> 1][jloc & 1] = jax_normal(KIN0, KIN1,
          (uint32_t)((jloc >> 1) * (BB * 2) + b * 2 + (jloc & 1)));
  }

  uint64_t* pub_b0 = pub + (size_t)b * HH;
  uint64_t* pub_b1 = pub + (size_t)(BB + b) * HH;
  float* __restrict__ hid_out = hids + (size_t)b * TT * HH;

  __syncthreads();

  for (int t = 0; t < TT; ++t) {
    const int par = t & 1;

    // Rotating output duty: block s==((t-1)&3) computes outs[b][t-1] from
    // rv = relu(h[t]) (off the critical chain of other blocks).
    if (t > 0 && s == ((t - 1) & 3)) {
      float v = rv * who_f;
      #pragma unroll
      for (int off = 32; off > 0; off >>= 1) v += __shfl_down(v, off);
      if (lane == 0) obuf[wv] = v;
    }

    // Owner prefetch into regs (pre-barrier; slot writes for t happened at
    // t-4 post-barrier, so barriers t-3..t-1 order them before these reads).
    float nr = 0.0f, ni0 = 0.0f, ni1 = 0.0f, x0 = 0.0f, x1 = 0.0f;
    if (isOwn) {
      nr  = nbuf[t & 3][jloc];
      ni0 = nin_s[t & 3][0];
      ni1 = nin_s[t & 3][1];
      x0  = stim_s[t];
      x1  = cc_s[t];
    }

    // Matvec partials — readlane-broadcast rv, register weights.
    float accA = 0.0f, accB = 0.0f;
    #pragma unroll
    for (int k = 0; k < 64; ++k) {
      float rk = __uint_as_float(__builtin_amdgcn_readlane(__float_as_uint(rv), k));
      accA = fmaf(rk, wA[k], accA);
      accB = fmaf(rk, wB[k], accB);
    }
    red[par][wv][lane]      = accA;
    red[par][wv][64 + lane] = accB;
    __syncthreads();  // the only barrier per step

    uint64_t* pub_t = par ? pub_b1 : pub_b0;

    if (isOwn) {
      // Combine (fixed order), update h, publish ASAP.
      float acc = red[par][0][jloc];
      #pragma unroll
      for (int w = 1; w < 8; ++w) acc += red[par][w][jloc];
      float hid_hid = acc + bhh + REC_SCALE_F * nr;
      float cur0 = fmaxf(x0 + IN_SCALE_F * ni0, 0.0f);
      float cur1 = fmaxf(x1 + IN_SCALE_F * ni1, 0.0f);
      float hid_in = cur0 * wih0 + cur1 * wih1;
      h = h + (-h + hid_in + hid_hid) * ALPHA_F;
      float r = fmaxf(h, 0.0f);
      uint64_t wd = ((uint64_t)(uint32_t)(t + 1) << 32) |
                    (uint64_t)__float_as_uint(r);
      __hip_atomic_store(&pub_t[tid], wd, __ATOMIC_RELAXED,
                         __HIP_MEMORY_SCOPE_AGENT);
      rv = r;  // own refresh is a register move
      __builtin_nontemporal_store(h, hid_out + (size_t)t * HH + tid);

      // Output-duty finalize (every 4th step for this block).
      if (tid == ownLo && t > 0 && s == ((t - 1) & 3)) {
        float psum = ((obuf[0] + obuf[1]) + (obuf[2] + obuf[3])) +
                     ((obuf[4] + obuf[5]) + (obuf[6] + obuf[7]));
        outs[b * TT + (t - 1)] = psum + bho;
      }

      // Regenerate noise for step t+4 in the slack window (slots are
      // owner-private; nin_s writes are barrier-ordered vs t+4 reads).
      if (t + 4 < TT) {
        nbuf[t & 3][jloc] = jax_normal(KRC0, KRC1,
            (uint32_t)(t + 4) * (uint32_t)(BB * HH) + (uint32_t)(b * HH + tid));
        if (jloc < 2)
          nin_s[t & 3][jloc] = jax_normal(KIN0, KIN1,
              (uint32_t)((t + 4) * (BB * 2) + b * 2 + jloc));
      }
    } else {
      // Remote refresh: 2-deep pipelined tagged-word poll.
      const uint32_t tagw = (uint32_t)(t + 1);
      uint64_t w = __hip_atomic_load(&pub_t[tid], __ATOMIC_RELAXED,
                                     __HIP_MEMORY_SCOPE_AGENT);
      if ((uint32_t)(w >> 32) != tagw) {
        uint64_t w2 = __hip_atomic_load(&pub_t[tid], __ATOMIC_RELAXED,
                                        __HIP_MEMORY_SCOPE_AGENT);
        int spins = 0;
        while ((uint32_t)(w >> 32) != tagw) {
          w = w2;
          if (++spins > 16) __builtin_amdgcn_s_sleep(1);
          w2 = __hip_atomic_load(&pub_t[tid], __ATOMIC_RELAXED,
                                 __HIP_MEMORY_SCOPE_AGENT);
        }
      }
      rv = __uint_as_float((uint32_t)w);
    }
  }

  // Tail: outs[TT-1] from final rv (duty block only; block-uniform branch).
  if (s == ((TT - 1) & 3)) {
    float v = rv * who_f;
    #pragma unroll
    for (int off = 32; off > 0; off >>= 1) v += __shfl_down(v, off);
    if (lane == 0) obuf[wv] = v;
    __syncthreads();
    if (tid == ownLo) {
      float psum = ((obuf[0] + obuf[1]) + (obuf[2] + obuf[3])) +
                   ((obuf[4] + obuf[5]) + (obuf[6] + obuf[7]));
      outs[b * TT + (TT - 1)] = psum + bho;
    }
  }
}

extern "C" void kernel_launch(void* const* d_in, const int* in_sizes, int n_in,
                              void* d_out, int out_size, void* d_ws, size_t ws_size,
                              hipStream_t stream) {
  const float* i_stim = (const float*)d_in[0];
  const float* i_cc   = (const float*)d_in[1];
  const float* hidden = (const float*)d_in[2];
  const float* w_ih   = (const float*)d_in[3];
  // d_in[4] = b_ih — never used by the reference
  const float* w_hh   = (const float*)d_in[5];
  const float* b_hh   = (const float*)d_in[6];
  const float* w_ho   = (const float*)d_in[7];
  const float* b_ho   = (const float*)d_in[8];

  float* outs   = (float*)d_out;                     // [B,T,O]
  float* hids   = (float*)d_out + (size_t)BB * TT;   // [B,T,H]
  uint64_t* pub = (uint64_t*)d_ws;

  // Kill stale tags from previous graph replays (tags strictly increase
  // within a run, so zeroed words can never falsely match).
  hipMemsetAsync(pub, 0, PUB_BYTES, stream);

  void* args[] = {(void*)&i_stim, (void*)&i_cc, (void*)&hidden, (void*)&w_ih,
                  (void*)&w_hh, (void*)&b_hh, (void*)&w_ho, (void*)&b_ho,
                  (void*)&outs, (void*)&hids, (void*)&pub};
  hipLaunchCooperativeKernel((const void*)zrnn_main, dim3(NBLK), dim3(512),
                             args, 0, stream);
}